// Round 2
// baseline (217.177 us; speedup 1.0000x reference)
//
#include <hip/hip_runtime.h>
#include <stdint.h>

#define NG 256      // num networks
#define KF 256      // IN_F
#define OF 256      // OUT_F
#define BM 128      // rows per tile
#define BK 64       // k-chunk
#define NKT 4       // KF / BK
#define NTILES 16   // PAD / BM
#define NTH 512     // 8 waves

typedef unsigned short ushort_t;
using f32x4  = __attribute__((ext_vector_type(4))) float;
using bf16x8 = __attribute__((ext_vector_type(8))) __bf16;
using u16x4  = __attribute__((ext_vector_type(4))) unsigned short;
using u16x8  = __attribute__((ext_vector_type(8))) unsigned short;

__device__ __forceinline__ unsigned short f2bf(float f) {
  unsigned u = __builtin_bit_cast(unsigned, f);
  u += 0x7fffu + ((u >> 16) & 1u);   // round-to-nearest-even
  return (unsigned short)(u >> 16);
}

// ---------------- offsets scan (1 block, 256 threads) ----------------
__global__ void scan_kernel(const int* __restrict__ counts, int* __restrict__ offs) {
  __shared__ int s[NG];
  int t = threadIdx.x;
  s[t] = counts[t];
  __syncthreads();
  #pragma unroll
  for (int d = 1; d < NG; d <<= 1) {
    int u = (t >= d) ? s[t - d] : 0;
    __syncthreads();
    s[t] += u;
    __syncthreads();
  }
  if (t == 0) offs[0] = 0;
  offs[t + 1] = s[t];
}

// ---------------- W f32 -> bf16 pre-swizzled LDS image ----------------
// img block (g,kc) = 32KB; ushort index ((o*8 + s)*8 + e) holds
// W[g][o][kc*64 + (s ^ (o&7))*8 + e]  -> linear global_load_lds produces
// the XOR-swizzled LDS layout directly.
__global__ __launch_bounds__(512)
void wconv_kernel(const float* __restrict__ w, unsigned short* __restrict__ img) {
  int tid = blockIdx.x * 512 + threadIdx.x;   // one 16B slot each
  int s  = tid & 7;
  int o  = (tid >> 3) & 255;
  int kc = (tid >> 11) & 3;
  int g  = tid >> 13;
  int k0 = kc * 64 + ((s ^ (o & 7)) << 3);
  const float* src = w + ((size_t)(g * 256 + o) * 256 + k0);
  f32x4 a = *(const f32x4*)src;
  f32x4 b = *(const f32x4*)(src + 4);
  u16x8 r;
  r[0]=f2bf(a[0]); r[1]=f2bf(a[1]); r[2]=f2bf(a[2]); r[3]=f2bf(a[3]);
  r[4]=f2bf(b[0]); r[5]=f2bf(b[1]); r[6]=f2bf(b[2]); r[7]=f2bf(b[3]);
  *(u16x8*)(img + (size_t)tid * 8) = r;
}

// ---------------- grouped GEMM ----------------
template<bool PRECONV>
__global__ __launch_bounds__(NTH)
void gemm_kernel(const float* __restrict__ x,
                 const float* __restrict__ wf32,
                 const unsigned short* __restrict__ wimg,
                 const float* __restrict__ bias,
                 const int* __restrict__ offs,
                 float* __restrict__ out)
{
  __shared__ __align__(16) unsigned short As[BM * BK];     // 16 KB
  __shared__ __align__(16) unsigned short Bs[2][OF * BK];  // 64 KB dbuf

  const int g      = blockIdx.y;
  const int r0     = offs[g];
  const int cnt    = offs[g + 1] - r0;
  const int tstart = blockIdx.x * BM;
  if (tstart >= cnt) return;
  const int mrows = min(BM, cnt - tstart);
  const int row0  = r0 + tstart;

  const int tid  = threadIdx.x;
  const int lane = tid & 63;
  const int wid  = tid >> 6;
  const int wm   = wid >> 2;     // 0..1
  const int wn   = wid & 3;      // 0..3
  const int lrow = lane & 15;
  const int lk   = lane >> 4;    // 0..3

  // A staging indices: idx = i*512 + tid; row = idx>>4; q (float4 within row) = idx&15
  int  arow_s[4], aq_s[4];
  bool aval[4];
  #pragma unroll
  for (int i = 0; i < 4; ++i) {
    int idx = i * NTH + tid;
    arow_s[i] = idx >> 4;
    aq_s[i]   = idx & 15;
    aval[i]   = arow_s[i] < mrows;
  }

  int arow_f[4], brow_f[4];
  #pragma unroll
  for (int m = 0; m < 4; ++m) arow_f[m] = wm * 64 + m * 16 + lrow;
  #pragma unroll
  for (int n = 0; n < 4; ++n) brow_f[n] = wn * 64 + n * 16 + lrow;

  f32x4 acc[4][4] = {};
  f32x4 aregs[4];
  f32x4 bregs[8];

  auto load_A = [&](int kt) {
    #pragma unroll
    for (int i = 0; i < 4; ++i) {
      if (aval[i])
        aregs[i] = *(const f32x4*)(x + (size_t)(row0 + arow_s[i]) * KF + kt * BK + aq_s[i] * 4);
      else
        aregs[i] = f32x4{0.f, 0.f, 0.f, 0.f};
    }
  };
  auto write_A = [&]() {
    #pragma unroll
    for (int i = 0; i < 4; ++i) {
      int row = arow_s[i], q = aq_s[i];
      int s   = q >> 1;
      int idx = row * 64 + (((s ^ (row & 7)) << 3)) + (q & 1) * 4;
      u16x4 v;
      v[0]=f2bf(aregs[i][0]); v[1]=f2bf(aregs[i][1]);
      v[2]=f2bf(aregs[i][2]); v[3]=f2bf(aregs[i][3]);
      *(u16x4*)&As[idx] = v;
    }
  };
  auto load_B_lds = [&](int kt, int buf) {
    const char* base = (const char*)wimg + ((size_t)(g * 4 + kt) << 15);
    #pragma unroll
    for (int j = 0; j < 4; ++j) {
      int c = wid * 4 + j;                        // 32 x 1KB chunks
      const void* gsrc = base + c * 1024 + lane * 16;
      void* ldst = (char*)&Bs[buf][0] + c * 1024; // wave-uniform dest
      __builtin_amdgcn_global_load_lds(
          (const __attribute__((address_space(1))) void*)gsrc,
          (__attribute__((address_space(3))) void*)ldst,
          16, 0, 0);
    }
  };
  auto load_B_reg = [&](int kt) {
    #pragma unroll
    for (int i = 0; i < 8; ++i) {
      int idx = i * NTH + tid;
      int ro = idx >> 4, q = idx & 15;
      bregs[i] = *(const f32x4*)(wf32 + (size_t)g * 65536 + (size_t)ro * 256 + kt * BK + q * 4);
    }
  };
  auto write_B_reg = [&](int buf) {
    #pragma unroll
    for (int i = 0; i < 8; ++i) {
      int idx = i * NTH + tid;
      int ro = idx >> 4, q = idx & 15;
      int s  = q >> 1;
      int lidx = ro * 64 + (((s ^ (ro & 7)) << 3)) + (q & 1) * 4;
      u16x4 v;
      v[0]=f2bf(bregs[i][0]); v[1]=f2bf(bregs[i][1]);
      v[2]=f2bf(bregs[i][2]); v[3]=f2bf(bregs[i][3]);
      *(u16x4*)&Bs[buf][lidx] = v;
    }
  };
  auto compute = [&](int buf) {
    #pragma unroll
    for (int kk = 0; kk < 2; ++kk) {
      bf16x8 af[4], bfr[4];
      #pragma unroll
      for (int m = 0; m < 4; ++m) {
        int row = arow_f[m];
        int s   = kk * 4 + lk;
        af[m] = *(const bf16x8*)&As[row * 64 + ((s ^ (row & 7)) << 3)];
      }
      #pragma unroll
      for (int n = 0; n < 4; ++n) {
        int row = brow_f[n];
        int s   = kk * 4 + lk;
        bfr[n] = *(const bf16x8*)&Bs[buf][row * 64 + ((s ^ (row & 7)) << 3)];
      }
      #pragma unroll
      for (int m = 0; m < 4; ++m)
        #pragma unroll
        for (int n = 0; n < 4; ++n)
          acc[m][n] = __builtin_amdgcn_mfma_f32_16x16x32_bf16(af[m], bfr[n], acc[m][n], 0, 0, 0);
    }
  };

  // prologue: stage tile 0
  load_A(0);
  if (PRECONV) load_B_lds(0, 0); else load_B_reg(0);
  write_A();
  if (!PRECONV) write_B_reg(0);
  __syncthreads();   // drains vmcnt (B tile 0 in LDS) + lgkm

  #pragma unroll
  for (int kt = 0; kt < NKT; ++kt) {
    const int  cur  = kt & 1;
    const bool more = (kt + 1) < NKT;
    if (more) {
      load_A(kt + 1);                               // global -> regs, no wait
      if (PRECONV) load_B_lds(kt + 1, cur ^ 1);     // direct to other buffer
      else         load_B_reg(kt + 1);
    }
    compute(cur);
    if (!PRECONV && more) write_B_reg(cur ^ 1);     // dbuf: safe pre-barrier
    if (more) {
      __syncthreads();  // all reads of As done; B(t+1) landed (vmcnt drain)
      write_A();        // cvt + ds_write next A tile
      __syncthreads();
    }
  }

  // epilogue: bias + guarded f32 stores
  float bb[4];
  #pragma unroll
  for (int n = 0; n < 4; ++n)
    bb[n] = bias[g * OF + wn * 64 + n * 16 + lrow];

  #pragma unroll
  for (int m = 0; m < 4; ++m) {
    int rb = wm * 64 + m * 16 + lk * 4;
    #pragma unroll
    for (int j = 0; j < 4; ++j) {
      int r = rb + j;
      if (r < mrows) {
        float* orow = out + (size_t)(row0 + r) * OF;
        #pragma unroll
        for (int n = 0; n < 4; ++n)
          orow[wn * 64 + n * 16 + lrow] = acc[m][n][j] + bb[n];
      }
    }
  }
}

extern "C" void kernel_launch(void* const* d_in, const int* in_sizes, int n_in,
                              void* d_out, int out_size, void* d_ws, size_t ws_size,
                              hipStream_t stream) {
  const float* weight = (const float*)d_in[0];
  const float* bias   = (const float*)d_in[1];
  const float* x      = (const float*)d_in[2];
  const int*   counts = (const int*)d_in[3];
  float* out = (float*)d_out;

  int* offs = (int*)d_ws;
  unsigned short* wimg = (unsigned short*)((char*)d_ws + 4096);
  const size_t need = 4096 + (size_t)NG * OF * KF * 2;  // ~32 MB

  scan_kernel<<<1, 256, 0, stream>>>(counts, offs);

  if (ws_size >= need) {
    wconv_kernel<<<(NG * 4 * 256 * 8) / 512, 512, 0, stream>>>(weight, wimg);
    gemm_kernel<true><<<dim3(NTILES, NG), NTH, 0, stream>>>(x, weight, wimg, bias, offs, out);
  } else {
    gemm_kernel<false><<<dim3(NTILES, NG), NTH, 0, stream>>>(x, weight, wimg, bias, offs, out);
  }
}